// Round 9
// baseline (90.151 us; speedup 1.0000x reference)
//
#include <hip/hip_runtime.h>
#include <hip/hip_fp16.h>

// Multi-scale deformable attention forward, MI355X.
// value: (2, 19947, 8, 32) f32 ; loc: (2, 19947, 8, 4, 4, 2) f32
// attw:  (2, 19947, 8, 4, 4) f32 ; out: (2, 19947, 256) f32
// R3: value transposed to (b,h,key,32ch) f16; (b,h) pinned to XCD (pair=blk&15).
// R4: packed-fp16 accumulation; x-weight via distance form max(0,1-|x-k|).
// R8: steady-state asm pipeline: 2 queries/thread x 4 levels = 8 chunks,
// 2-buffer rotation, params for chunk c+1 issued BEFORE gathers of chunk c
// so counted vmcnt(11)/vmcnt(8) never drains; 16-19 loads in flight.

#define KQ 19947
#define NBQ (2 * KQ)

// ---------- transpose + convert: (b,k,h,32) f32 -> (b*8+h, k, 32) f16 ----------
__global__ __launch_bounds__(256) void transpose_f16(
    const float* __restrict__ V, __half* __restrict__ Vh)
{
    const int pair = blockIdx.y;                    // b*8+h
    const int j = blockIdx.x * 256 + threadIdx.x;   // (k, cg) flat, cg = 8ch group
    if (j >= KQ * 4) return;
    const int k = j >> 2, cg = j & 3;
    const int b = pair >> 3, h = pair & 7;
    const float* src = V + (((size_t)b * KQ + k) * 8 + h) * 32 + cg * 8;
    const float4 a0 = *reinterpret_cast<const float4*>(src);
    const float4 a1 = *reinterpret_cast<const float4*>(src + 4);
    __half2 h0 = __floats2half2_rn(a0.x, a0.y);
    __half2 h1 = __floats2half2_rn(a0.z, a0.w);
    __half2 h2 = __floats2half2_rn(a1.x, a1.y);
    __half2 h3 = __floats2half2_rn(a1.z, a1.w);
    uint4 o;
    o.x = *reinterpret_cast<unsigned int*>(&h0);
    o.y = *reinterpret_cast<unsigned int*>(&h1);
    o.z = *reinterpret_cast<unsigned int*>(&h2);
    o.w = *reinterpret_cast<unsigned int*>(&h3);
    reinterpret_cast<uint4*>(Vh + ((size_t)pair * KQ) * 32)[j] = o;
}

// addr/weight math for one level; emits 8 byte-offsets (incl. lane base) + weights
template<int L>
static __device__ __forceinline__ void addr_level(
    float4 pg0, float4 pg1, float4 pw,
    float slotf, int g_base, int* off, float* cw)
{
    constexpr int Hh = (L == 0) ? 100 : (L == 1) ? 50 : (L == 2) ? 25 : 13;
    constexpr int Ww = (L == 0) ? 150 : (L == 1) ? 75 : (L == 2) ? 38 : 19;
    constexpr int st = (L == 0) ? 0 : (L == 1) ? 15000 : (L == 2) ? 18750 : 19700;
    const float Hf = (float)Hh, Wf = (float)Ww;
    const float lx[4] = {pg0.x, pg0.z, pg1.x, pg1.z};
    const float ly[4] = {pg0.y, pg0.w, pg1.y, pg1.w};
    const float ww[4] = {pw.x, pw.y, pw.z, pw.w};
    #pragma unroll
    for (int p = 0; p < 4; ++p) {
        const float x = fmaf(lx[p], Wf, -0.5f);
        const float y = fmaf(ly[p], Hf, -0.5f);
        const float fy = floorf(y);
        const int y0 = (int)fy;
        const int x0 = (int)floorf(x);
        // x0 in [-1, W-1]; bx in [0, W-2] -> keys bx, bx+1 distinct, in bounds.
        const int bx = min(max(x0, 0), Ww - 2);
        // this lane's key = bx + slot; x-weight = max(0, 1-|x-k|).
        const float wxl = fmaxf(0.f, 1.f - fabsf(x - ((float)bx + slotf)));
        const float wy1 = y - fy, wy0 = 1.f - wy1;
        const int y0c = max(y0, 0);
        const int y1c = min(y0 + 1, Hh - 1);
        const float ay0 = (y0 >= 0)     ? wy0 : 0.f;
        const float ay1 = (y0 + 1 < Hh) ? wy1 : 0.f;
        const float wl = ww[p] * wxl;
        off[2*p]   = ((st + y0c * Ww + bx) << 6) + g_base;
        off[2*p+1] = ((st + y1c * Ww + bx) << 6) + g_base;
        cw[2*p]    = wl * ay0;
        cw[2*p+1]  = wl * ay1;
    }
}

static __device__ __forceinline__ void consume_level(
    const uint4* v, const float* cw, float* acc)
{
    __half2 accH[4];
    #pragma unroll
    for (int j = 0; j < 4; ++j) accH[j] = __half2(__half(0.f), __half(0.f));
    #pragma unroll
    for (int i = 0; i < 8; ++i) {
        const __half2 wh = __floats2half2_rn(cw[i], cw[i]);
        union { uint4 u; __half2 h2[4]; } uv;
        uv.u = v[i];
        #pragma unroll
        for (int j = 0; j < 4; ++j)
            accH[j] = __hfma2(wh, uv.h2[j], accH[j]);
    }
    #pragma unroll
    for (int j = 0; j < 4; ++j) {
        const float2 f = __half22float2(accH[j]);
        acc[2*j]   += f.x;
        acc[2*j+1] += f.y;
    }
}

// 3 param loads for chunk (lbase = loc byte base, wbase = attw byte base, level l)
#define PLOAD(l, lbase, wbase)                                               \
    asm volatile("global_load_dwordx4 %0, %1, %2"                            \
                 : "=v"(pg0) : "v"((lbase) + (l) * 32), "s"(LOC));           \
    asm volatile("global_load_dwordx4 %0, %1, %2"                            \
                 : "=v"(pg1) : "v"((lbase) + (l) * 32 + 16), "s"(LOC));      \
    asm volatile("global_load_dwordx4 %0, %1, %2"                            \
                 : "=v"(pw)  : "v"((wbase) + (l) * 16), "s"(W))

#define GLOAD8(buf)                                                          \
    {                                                                        \
        _Pragma("unroll")                                                    \
        for (int i = 0; i < 8; ++i)                                          \
            asm volatile("global_load_dwordx4 %0, %1, %2"                    \
                         : "=v"(buf[i]) : "v"(off[i]), "s"(Vh));             \
    }

#define VWAIT(n)                                                             \
    asm volatile("s_waitcnt vmcnt(" #n ")" ::: "memory");                    \
    __builtin_amdgcn_sched_barrier(0)

// ---------- gather: block = one (b,h) x 64 queries; 8 lanes per query ----------
__global__ __launch_bounds__(256, 3) void msda_fwd_t(
    const __half* __restrict__ Vh,
    const float* __restrict__ LOC,
    const float* __restrict__ W,
    float* __restrict__ OUT)
{
    const int pair = blockIdx.x & 15;               // b*8+h -> XCD = blk % 8
    const int qc   = blockIdx.x >> 4;
    const int tid  = threadIdx.x;
    const int s    = tid & 7;                       // slot = s>>2, chgrp = s&3
    const int slot = s >> 2;
    const float slotf = (float)slot;
    const int q0   = qc * 64 + (tid >> 3);          // < KQ always (qc <= 311)
    const int q1   = q0 + 32;
    const int q1c  = min(q1, KQ - 1);
    const int b = pair >> 3, h = pair & 7;

    // byte bases
    const int g_base = pair * KQ * 64 + s * 16;     // value gather lane base
    const int lb0 = (((b * KQ + q0) * 8) + h) << 7; // loc row (32 f32 = 128 B)
    const int wb0 = (((b * KQ + q0) * 8) + h) << 6; // attw row (16 f32 = 64 B)
    const int lb1 = (((b * KQ + q1c) * 8) + h) << 7;
    const int wb1 = (((b * KQ + q1c) * 8) + h) << 6;

    float acc0[8], acc1[8];
    #pragma unroll
    for (int c = 0; c < 8; ++c) { acc0[c] = 0.f; acc1[c] = 0.f; }

    float4 pg0, pg1, pw;                            // rotating param regs
    int off[8];                                     // transient per chunk
    uint4 bufA[8], bufB[8];
    float cwA[8], cwB[8];

    // ---- prologue ----
    PLOAD(0, lb0, wb0);                             // P(c0)          out:3
    VWAIT(0);                                       // params c0 ready
    addr_level<0>(pg0, pg1, pw, slotf, g_base, off, cwA);
    PLOAD(1, lb0, wb0);                             // P(c1)          out:3
    GLOAD8(bufA);                                   // G(c0)          out:11
    VWAIT(8);                                       // params c1 ready

    // ---- steady state: chunks 1..6 ----
    addr_level<1>(pg0, pg1, pw, slotf, g_base, off, cwB);
    PLOAD(2, lb0, wb0);                             // P(c2)          out:11
    GLOAD8(bufB);                                   // G(c1)          out:19
    VWAIT(11);                                      // G(c0) done
    consume_level(bufA, cwA, acc0);
    VWAIT(8);                                       // params c2 ready

    addr_level<2>(pg0, pg1, pw, slotf, g_base, off, cwA);
    PLOAD(3, lb0, wb0);                             // P(c3)
    GLOAD8(bufA);                                   // G(c2)
    VWAIT(11);                                      // G(c1) done
    consume_level(bufB, cwB, acc0);
    VWAIT(8);                                       // params c3 ready

    addr_level<3>(pg0, pg1, pw, slotf, g_base, off, cwB);
    PLOAD(0, lb1, wb1);                             // P(c4) (q1, l0)
    GLOAD8(bufB);                                   // G(c3)
    VWAIT(11);                                      // G(c2) done
    consume_level(bufA, cwA, acc0);
    VWAIT(8);                                       // params c4 ready

    addr_level<0>(pg0, pg1, pw, slotf, g_base, off, cwA);
    PLOAD(1, lb1, wb1);                             // P(c5)
    GLOAD8(bufA);                                   // G(c4)
    VWAIT(11);                                      // G(c3) done
    consume_level(bufB, cwB, acc0);
    VWAIT(8);                                       // params c5 ready

    addr_level<1>(pg0, pg1, pw, slotf, g_base, off, cwB);
    PLOAD(2, lb1, wb1);                             // P(c6)
    GLOAD8(bufB);                                   // G(c5)
    VWAIT(11);                                      // G(c4) done
    consume_level(bufA, cwA, acc1);
    VWAIT(8);                                       // params c6 ready

    addr_level<2>(pg0, pg1, pw, slotf, g_base, off, cwA);
    PLOAD(3, lb1, wb1);                             // P(c7)
    GLOAD8(bufA);                                   // G(c6)
    VWAIT(11);                                      // G(c5) done
    consume_level(bufB, cwB, acc1);
    VWAIT(8);                                       // params c7 ready

    // ---- epilogue: chunk 7 ----
    addr_level<3>(pg0, pg1, pw, slotf, g_base, off, cwB);
    GLOAD8(bufB);                                   // G(c7)          out:16
    VWAIT(8);                                       // G(c6) done
    consume_level(bufA, cwA, acc1);
    VWAIT(0);                                       // G(c7) done
    consume_level(bufB, cwB, acc1);

    // combine the two key-slots: lanes s and s^4 hold the two x-corners
    #pragma unroll
    for (int c = 0; c < 8; ++c) {
        acc0[c] += __shfl_xor(acc0[c], 4, 64);
        acc1[c] += __shfl_xor(acc1[c], 4, 64);
    }

    // lane s writes channels chgrp*8 + slot*4 .. +4
    const int co = h * 32 + (s & 3) * 8 + slot * 4;
    float* op0 = OUT + ((size_t)b * KQ + q0) * 256 + co;
    *reinterpret_cast<float4*>(op0) =
        make_float4(acc0[slot*4], acc0[slot*4+1], acc0[slot*4+2], acc0[slot*4+3]);
    if (q1 < KQ) {
        float* op1 = OUT + ((size_t)b * KQ + q1) * 256 + co;
        *reinterpret_cast<float4*>(op1) =
            make_float4(acc1[slot*4], acc1[slot*4+1], acc1[slot*4+2], acc1[slot*4+3]);
    }
}

// ---------- f32 fallback (no workspace needed) ----------
static __device__ __forceinline__ void fmadd4(float4& a, float s, const float4 v) {
    a.x = fmaf(s, v.x, a.x);
    a.y = fmaf(s, v.y, a.y);
    a.z = fmaf(s, v.z, a.z);
    a.w = fmaf(s, v.w, a.w);
}

__global__ __launch_bounds__(256, 4) void msda_fwd_f32(
    const float* __restrict__ V,
    const float* __restrict__ LOC,
    const float* __restrict__ W,
    float* __restrict__ OUT)
{
    const int t  = blockIdx.x * 256 + threadIdx.x;
    const int cg = t & 7;
    const int h  = (t >> 3) & 7;
    const int bq = t >> 6;
    if (bq >= NBQ) return;
    const int b = (bq >= KQ) ? 1 : 0;

    const int Hs[4]  = {100, 50, 25, 13};
    const int Ws[4]  = {150, 75, 38, 19};
    const int STs[4] = {0, 15000, 18750, 19700};

    const int hoff = (h << 5) + (cg << 2);
    const float* vb = V + (size_t)b * KQ * 256 + hoff;
    const float* lp = LOC + ((size_t)bq * 8 + h) * 32;
    const float* wp = W   + ((size_t)bq * 8 + h) * 16;

    float4 acc = make_float4(0.f, 0.f, 0.f, 0.f);

    #pragma unroll
    for (int l = 0; l < 4; ++l) {
        const int Hh = Hs[l], Ww = Ws[l], st = STs[l];
        const float Hf = (float)Hh, Wf = (float)Ww;
        const float4 w4 = *reinterpret_cast<const float4*>(wp + l * 4);
        const float4 g0 = *reinterpret_cast<const float4*>(lp + l * 8);
        const float4 g1 = *reinterpret_cast<const float4*>(lp + l * 8 + 4);
        const float lx[4] = {g0.x, g0.z, g1.x, g1.z};
        const float ly[4] = {g0.y, g0.w, g1.y, g1.w};
        const float ww[4] = {w4.x, w4.y, w4.z, w4.w};
        #pragma unroll
        for (int p = 0; p < 4; ++p) {
            const float x = fmaf(lx[p], Wf, -0.5f);
            const float y = fmaf(ly[p], Hf, -0.5f);
            const float fx = floorf(x), fy = floorf(y);
            const int x0 = (int)fx, y0 = (int)fy;
            const float wx1 = x - fx, wy1 = y - fy;
            const float wx0 = 1.f - wx1, wy0 = 1.f - wy1;
            const int x0c = max(x0, 0),     x1c = min(x0 + 1, Ww - 1);
            const int y0c = max(y0, 0),     y1c = min(y0 + 1, Hh - 1);
            const float ax0 = (x0 >= 0)      ? wx0 : 0.f;
            const float ax1 = (x0 + 1 < Ww)  ? wx1 : 0.f;
            const float ay0 = (y0 >= 0)      ? wy0 : 0.f;
            const float ay1 = (y0 + 1 < Hh)  ? wy1 : 0.f;
            const float w = ww[p];
            const int b0 = st + y0c * Ww, b1 = st + y1c * Ww;
            fmadd4(acc, w*ay0*ax0, *reinterpret_cast<const float4*>(vb + ((b0+x0c) << 8)));
            fmadd4(acc, w*ay0*ax1, *reinterpret_cast<const float4*>(vb + ((b0+x1c) << 8)));
            fmadd4(acc, w*ay1*ax0, *reinterpret_cast<const float4*>(vb + ((b1+x0c) << 8)));
            fmadd4(acc, w*ay1*ax1, *reinterpret_cast<const float4*>(vb + ((b1+x1c) << 8)));
        }
    }
    *reinterpret_cast<float4*>(OUT + (size_t)bq * 256 + hoff) = acc;
}

extern "C" void kernel_launch(void* const* d_in, const int* in_sizes, int n_in,
                              void* d_out, int out_size, void* d_ws, size_t ws_size,
                              hipStream_t stream) {
    const float* V   = (const float*)d_in[0];
    const float* LOC = (const float*)d_in[2];
    const float* W   = (const float*)d_in[3];
    float* OUT = (float*)d_out;

    const size_t n_val = (size_t)2 * KQ * 256;          // 10,212,864 halves
    const size_t need  = n_val * sizeof(__half) + 256;  // ~20.4 MB

    if (ws_size >= need) {
        __half* Vh = (__half*)d_ws;
        const int jtot = KQ * 4;                        // (k, cg) per pair
        dim3 tgrid((jtot + 255) / 256, 16);
        hipLaunchKernelGGL(transpose_f16, tgrid, dim3(256), 0, stream, V, Vh);

        const int qchunks = (KQ + 63) / 64;             // 312
        const int blocks  = qchunks * 16;               // 4992
        hipLaunchKernelGGL(msda_fwd_t, dim3(blocks), dim3(256), 0, stream,
                           Vh, LOC, W, OUT);
    } else {
        const int total = NBQ * 64;
        hipLaunchKernelGGL(msda_fwd_f32, dim3((total + 255) / 256), dim3(256), 0, stream,
                           V, LOC, W, OUT);
    }
}

// Round 11
// 84.523 us; speedup vs baseline: 1.0666x; 1.0666x over previous
//
#include <hip/hip_runtime.h>
#include <hip/hip_fp16.h>

// Multi-scale deformable attention forward, MI355X.
// value: (2, 19947, 8, 32) f32 ; loc: (2, 19947, 8, 4, 4, 2) f32
// attw:  (2, 19947, 8, 4, 4) f32 ; out: (2, 19947, 256) f32
// R3: value transposed to (b,h,key,32ch) f16; (b,h) pinned to XCD via
// pair = blk & 15 (XCD = blk % 8) -> 2.56 MB L2 set; row-pair 128B loads.
// R4: packed-fp16 accumulation; x-weight via distance form max(0,1-|x-k|).
// R7: asm-forced gather pipeline -- volatile global_load_dwordx4 + counted
// s_waitcnt vmcnt(N) + sched_barrier(0), 3-buffer rotation, 16-24 in flight.
// R10: lane-dedup of the address/weight math: lane j of each 8-lane query
// group computes points j and j+8 once, broadcasts the 5 slot-invariant
// values via __shfl (ds_bpermute, lgkm pipe -- never disturbs vmcnt);
// consumers apply only wxl = max(0,1-|dx-slot|). ~3x less addr VALU.
// LESSON (R9): never tighten launch_bounds near the VGPR count -- spills go
// to scratch, scratch counts in vmcnt, and manual VWAIT counting corrupts.

#define KQ 19947
#define NBQ (2 * KQ)

// ---------- transpose + convert: (b,k,h,32) f32 -> (b*8+h, k, 32) f16 ----------
__global__ __launch_bounds__(256) void transpose_f16(
    const float* __restrict__ V, __half* __restrict__ Vh)
{
    const int pair = blockIdx.y;                    // b*8+h
    const int j = blockIdx.x * 256 + threadIdx.x;   // (k, cg) flat, cg = 8ch group
    if (j >= KQ * 4) return;
    const int k = j >> 2, cg = j & 3;
    const int b = pair >> 3, h = pair & 7;
    const float* src = V + (((size_t)b * KQ + k) * 8 + h) * 32 + cg * 8;
    const float4 a0 = *reinterpret_cast<const float4*>(src);
    const float4 a1 = *reinterpret_cast<const float4*>(src + 4);
    __half2 h0 = __floats2half2_rn(a0.x, a0.y);
    __half2 h1 = __floats2half2_rn(a0.z, a0.w);
    __half2 h2 = __floats2half2_rn(a1.x, a1.y);
    __half2 h3 = __floats2half2_rn(a1.z, a1.w);
    uint4 o;
    o.x = *reinterpret_cast<unsigned int*>(&h0);
    o.y = *reinterpret_cast<unsigned int*>(&h1);
    o.z = *reinterpret_cast<unsigned int*>(&h2);
    o.w = *reinterpret_cast<unsigned int*>(&h3);
    reinterpret_cast<uint4*>(Vh + ((size_t)pair * KQ) * 32)[j] = o;
}

// Shared (slot-invariant) math for one sample point. Lane j handles point
// pt = j + 8*ROUND; level = 2*ROUND + (j>>2), p = j&3.
template<int ROUND>
static __device__ __forceinline__ void shared_point(
    int j, float2 g, float w,
    int& offb0, int& offb1, float& dxx, float& wy0w, float& wy1w)
{
    const bool hi = (j & 4) != 0;
    const int Wl = (ROUND == 0) ? (hi ? 75 : 150) : (hi ? 19 : 38);
    const int Hl = (ROUND == 0) ? (hi ? 50 : 100) : (hi ? 13 : 25);
    const int st = (ROUND == 0) ? (hi ? 15000 : 0) : (hi ? 19700 : 18750);
    const float Wf = (float)Wl, Hf = (float)Hl;
    const float x = fmaf(g.x, Wf, -0.5f);
    const float y = fmaf(g.y, Hf, -0.5f);
    const float fy = floorf(y);
    const int y0 = (int)fy;
    const int x0 = (int)floorf(x);
    // x0 in [-1, W-1]; bx in [0, W-2] -> keys bx, bx+1 distinct, in bounds.
    const int bx = min(max(x0, 0), Wl - 2);
    dxx = x - (float)bx;                 // consumer: wxl = max(0,1-|dxx-slot|)
    const float wy1 = y - fy, wy0 = 1.f - wy1;
    const int y0c = max(y0, 0);
    const int y1c = min(y0 + 1, Hl - 1);
    const float ay0 = (y0 >= 0) ? wy0 : 0.f;
    const float ay1 = (y0 + 1 < Hl) ? wy1 : 0.f;
    wy0w = w * ay0;
    wy1w = w * ay1;
    offb0 = (st + y0c * Wl + bx) << 5;   // half-elem offset, lane base in vbl
    offb1 = (st + y1c * Wl + bx) << 5;
}

static __device__ __forceinline__ void consume_level(
    const uint4* v, const float* cw, float acc[8])
{
    __half2 accH[4];
    #pragma unroll
    for (int j = 0; j < 4; ++j) accH[j] = __half2(__half(0.f), __half(0.f));
    #pragma unroll
    for (int i = 0; i < 8; ++i) {
        const __half2 wh = __floats2half2_rn(cw[i], cw[i]);
        union { uint4 u; __half2 h2[4]; } uv;
        uv.u = v[i];
        #pragma unroll
        for (int j = 0; j < 4; ++j)
            accH[j] = __hfma2(wh, uv.h2[j], accH[j]);
    }
    #pragma unroll
    for (int j = 0; j < 4; ++j) {
        const float2 f = __half22float2(accH[j]);
        acc[2*j]   += f.x;
        acc[2*j+1] += f.y;
    }
}

#define GLOAD8(buf, obase)                                                   \
    {                                                                        \
        _Pragma("unroll")                                                    \
        for (int i = 0; i < 8; ++i) {                                        \
            const __half* p_ = vbl + (obase)[i];                             \
            asm volatile("global_load_dwordx4 %0, %1, off"                   \
                         : "=v"(buf[i]) : "v"(p_));                          \
        }                                                                    \
    }
#define VWAIT(n)                                                             \
    asm volatile("s_waitcnt vmcnt(" #n ")" ::: "memory");                    \
    __builtin_amdgcn_sched_barrier(0)
#define SBAR() __builtin_amdgcn_sched_barrier(0)

// ---------- gather: block = one (b,h) x 32 queries; 8 lanes per query ----------
__global__ __launch_bounds__(256, 3) void msda_fwd_t(
    const __half* __restrict__ Vh,
    const float* __restrict__ LOC,
    const float* __restrict__ W,
    float* __restrict__ OUT)
{
    const int pair = blockIdx.x & 15;               // b*8+h -> XCD = blk % 8
    const int qc   = blockIdx.x >> 4;
    const int tid  = threadIdx.x;
    const int s    = tid & 7;                       // slot = s>>2, chgrp = s&3
    const int slot = s >> 2;
    const float slotf = (float)slot;
    const int q    = qc * 32 + (tid >> 3);
    if (q >= KQ) return;
    const int b = pair >> 3, h = pair & 7;
    const int ln = tid & 63;                        // lane in wave
    const int gb = ln & 56;                         // query-group base lane

    // lane base: + s*8 halves covers [key base+slot, channels chgrp*8..+8)
    const __half* vbl = Vh + (size_t)pair * KQ * 32 + s * 8;
    const float* lp = LOC + (((size_t)b * KQ + q) * 8 + h) * 32;
    const float* wp = W   + (((size_t)b * KQ + q) * 8 + h) * 16;

    float acc[8];
    #pragma unroll
    for (int c = 0; c < 8; ++c) acc[c] = 0.f;

    // ---- dedup addr math: lane j computes points j and j+8 once ----
    // loc row layout: [l][p][2] floats -> point pt at float offset 2*pt;
    // attw row: [l][p] -> offset pt.
    const float2 gA = *reinterpret_cast<const float2*>(lp + 2 * s);
    const float  wA = wp[s];
    const float2 gB = *reinterpret_cast<const float2*>(lp + 2 * s + 16);
    const float  wB = wp[s + 8];

    int ob0A, ob1A, ob0B, ob1B;
    float dxA, u0A, u1A, dxB, u0B, u1B;
    shared_point<0>(s, gA, wA, ob0A, ob1A, dxA, u0A, u1A);
    shared_point<1>(s, gB, wB, ob0B, ob1B, dxB, u0B, u1B);

    // ---- broadcast + per-slot finish: off/cw for all 16 points ----
    int off[32];
    float cw[32];
    #pragma unroll
    for (int pt = 0; pt < 8; ++pt) {                // points 0..7 (levels 0,1)
        const int src = gb + pt;
        const int   o0 = __shfl(ob0A, src, 64);
        const int   o1 = __shfl(ob1A, src, 64);
        const float dx = __shfl(dxA,  src, 64);
        const float u0 = __shfl(u0A,  src, 64);
        const float u1 = __shfl(u1A,  src, 64);
        const float wxl = fmaxf(0.f, 1.f - fabsf(dx - slotf));
        off[2*pt]   = o0;
        off[2*pt+1] = o1;
        cw[2*pt]    = u0 * wxl;
        cw[2*pt+1]  = u1 * wxl;
    }
    #pragma unroll
    for (int pt = 0; pt < 8; ++pt) {                // points 8..15 (levels 2,3)
        const int src = gb + pt;
        const int   o0 = __shfl(ob0B, src, 64);
        const int   o1 = __shfl(ob1B, src, 64);
        const float dx = __shfl(dxB,  src, 64);
        const float u0 = __shfl(u0B,  src, 64);
        const float u1 = __shfl(u1B,  src, 64);
        const float wxl = fmaxf(0.f, 1.f - fabsf(dx - slotf));
        off[16+2*pt]   = o0;
        off[16+2*pt+1] = o1;
        cw[16+2*pt]    = u0 * wxl;
        cw[16+2*pt+1]  = u1 * wxl;
    }

    // drain compiler-issued vmem (loc/attw) so manual vmcnt counts are exact
    VWAIT(0);

    uint4 va[8], vb2[8], vc[8];
    GLOAD8(va,  off + 0);                 // l0: 8 outstanding
    GLOAD8(vb2, off + 8);                 // l1: 16 outstanding
    VWAIT(8);                             // l0 ready
    GLOAD8(vc,  off + 16);                // l2: 16 outstanding
    SBAR();
    consume_level(va, cw + 0, acc);       // level 0
    SBAR();                               // pin consume before va reuse
    GLOAD8(va,  off + 24);                // l3: <= 24 outstanding
    VWAIT(16);                            // l1 ready (l2, l3 in flight)
    consume_level(vb2, cw + 8, acc);      // level 1
    VWAIT(8);                             // l2 ready
    consume_level(vc, cw + 16, acc);      // level 2
    VWAIT(0);                             // l3 ready
    consume_level(va, cw + 24, acc);      // level 3

    // combine the two key-slots: lanes s and s^4 hold the two x-corners
    #pragma unroll
    for (int c = 0; c < 8; ++c)
        acc[c] += __shfl_xor(acc[c], 4, 64);

    // lane s writes channels chgrp*8 + slot*4 .. +4  (values acc[slot*4..+4))
    float* op = OUT + ((size_t)b * KQ + q) * 256 + h * 32 + (s & 3) * 8 + slot * 4;
    *reinterpret_cast<float4*>(op) =
        make_float4(acc[slot*4], acc[slot*4+1], acc[slot*4+2], acc[slot*4+3]);
}

// ---------- f32 fallback (no workspace needed) ----------
static __device__ __forceinline__ void fmadd4(float4& a, float s, const float4 v) {
    a.x = fmaf(s, v.x, a.x);
    a.y = fmaf(s, v.y, a.y);
    a.z = fmaf(s, v.z, a.z);
    a.w = fmaf(s, v.w, a.w);
}

__global__ __launch_bounds__(256, 4) void msda_fwd_f32(
    const float* __restrict__ V,
    const float* __restrict__ LOC,
    const float* __restrict__ W,
    float* __restrict__ OUT)
{
    const int t  = blockIdx.x * 256 + threadIdx.x;
    const int cg = t & 7;
    const int h  = (t >> 3) & 7;
    const int bq = t >> 6;
    if (bq >= NBQ) return;
    const int b = (bq >= KQ) ? 1 : 0;

    const int Hs[4]  = {100, 50, 25, 13};
    const int Ws[4]  = {150, 75, 38, 19};
    const int STs[4] = {0, 15000, 18750, 19700};

    const int hoff = (h << 5) + (cg << 2);
    const float* vb = V + (size_t)b * KQ * 256 + hoff;
    const float* lp = LOC + ((size_t)bq * 8 + h) * 32;
    const float* wp = W   + ((size_t)bq * 8 + h) * 16;

    float4 acc = make_float4(0.f, 0.f, 0.f, 0.f);

    #pragma unroll
    for (int l = 0; l < 4; ++l) {
        const int Hh = Hs[l], Ww = Ws[l], st = STs[l];
        const float Hf = (float)Hh, Wf = (float)Ww;
        const float4 w4 = *reinterpret_cast<const float4*>(wp + l * 4);
        const float4 g0 = *reinterpret_cast<const float4*>(lp + l * 8);
        const float4 g1 = *reinterpret_cast<const float4*>(lp + l * 8 + 4);
        const float lx[4] = {g0.x, g0.z, g1.x, g1.z};
        const float ly[4] = {g0.y, g0.w, g1.y, g1.w};
        const float ww[4] = {w4.x, w4.y, w4.z, w4.w};
        #pragma unroll
        for (int p = 0; p < 4; ++p) {
            const float x = fmaf(lx[p], Wf, -0.5f);
            const float y = fmaf(ly[p], Hf, -0.5f);
            const float fx = floorf(x), fy = floorf(y);
            const int x0 = (int)fx, y0 = (int)fy;
            const float wx1 = x - fx, wy1 = y - fy;
            const float wx0 = 1.f - wx1, wy0 = 1.f - wy1;
            const int x0c = max(x0, 0),     x1c = min(x0 + 1, Ww - 1);
            const int y0c = max(y0, 0),     y1c = min(y0 + 1, Hh - 1);
            const float ax0 = (x0 >= 0)      ? wx0 : 0.f;
            const float ax1 = (x0 + 1 < Ww)  ? wx1 : 0.f;
            const float ay0 = (y0 >= 0)      ? wy0 : 0.f;
            const float ay1 = (y0 + 1 < Hh)  ? wy1 : 0.f;
            const float w = ww[p];
            const int b0 = st + y0c * Ww, b1 = st + y1c * Ww;
            fmadd4(acc, w*ay0*ax0, *reinterpret_cast<const float4*>(vb + ((b0+x0c) << 8)));
            fmadd4(acc, w*ay0*ax1, *reinterpret_cast<const float4*>(vb + ((b0+x1c) << 8)));
            fmadd4(acc, w*ay1*ax0, *reinterpret_cast<const float4*>(vb + ((b1+x0c) << 8)));
            fmadd4(acc, w*ay1*ax1, *reinterpret_cast<const float4*>(vb + ((b1+x1c) << 8)));
        }
    }
    *reinterpret_cast<float4*>(OUT + (size_t)bq * 256 + hoff) = acc;
}

extern "C" void kernel_launch(void* const* d_in, const int* in_sizes, int n_in,
                              void* d_out, int out_size, void* d_ws, size_t ws_size,
                              hipStream_t stream) {
    const float* V   = (const float*)d_in[0];
    const float* LOC = (const float*)d_in[2];
    const float* W   = (const float*)d_in[3];
    float* OUT = (float*)d_out;

    const size_t n_val = (size_t)2 * KQ * 256;          // 10,212,864 halves
    const size_t need  = n_val * sizeof(__half) + 256;  // ~20.4 MB

    if (ws_size >= need) {
        __half* Vh = (__half*)d_ws;
        const int jtot = KQ * 4;                        // (k, cg) per pair
        dim3 tgrid((jtot + 255) / 256, 16);
        hipLaunchKernelGGL(transpose_f16, tgrid, dim3(256), 0, stream, V, Vh);

        const int qchunks = (KQ + 31) / 32;             // 624
        const int blocks  = qchunks * 16;               // 9984
        hipLaunchKernelGGL(msda_fwd_t, dim3(blocks), dim3(256), 0, stream,
                           Vh, LOC, W, OUT);
    } else {
        const int total = NBQ * 64;
        hipLaunchKernelGGL(msda_fwd_f32, dim3((total + 255) / 256), dim3(256), 0, stream,
                           V, LOC, W, OUT);
    }
}